// Round 2
// baseline (213.939 us; speedup 1.0000x reference)
//
#include <hip/hip_runtime.h>
#include <math.h>

// fab_penalty_ls_curve: curvature penalty over mirrored level-set field.
// R2: fast-math (v_rcp/v_sqrt/minimax atan), register rotation over rows
// (13 -> 5 loads/point), interior/boundary template split, fp32 per-thread
// accumulation, fused final reduction via f64 atomic + last-block-out.
// Mirror-half trick (R1, verified absmax 0.0): compute left half only, x2.

#define BLOCK_X 256
#define ROWS_PER 16

// atan(v / c) with v > 0, given rv ~= 1/v (reused from k = num*rv^3).
// Max abs error ~1e-5 rad; budget is ~1e3x larger (2% on the sum).
__device__ __forceinline__ float fast_atan_ratio(float v, float c, float rv)
{
    const float rc = __builtin_amdgcn_rcpf(c);
    const float q  = v * rc;        // v/c (sign = sign(c))
    const float iq = c * rv;        // c/v = 1/q, no extra rcp
    const bool  big = fabsf(q) > 1.0f;
    const float t  = big ? iq : q;
    const float s  = t * t;
    float p = fmaf(s, -0.01172120f, 0.05265332f);
    p = fmaf(s, p, -0.11643287f);
    p = fmaf(s, p,  0.19354346f);
    p = fmaf(s, p, -0.33262347f);
    p = fmaf(s, p,  0.99997726f);
    const float at = p * t;
    const float hp = copysignf(1.57079632679f, q);
    return big ? (hp - at) : at;    // atan(q) = sign(q)*pi/2 - atan(1/q), |q|>1
}

template<bool INT>
__device__ __forceinline__ float compute_rows(
    const float* __restrict__ eps, int Hn, int Wn, int i0,
    int j, int jm, int jmm, int cjp, int cjpp,
    float rd, float syj, float sym, float syp)
{
    const float rd2 = 0.5f * rd;
    const float SC = 1e-12f;
    const float FLOORV = (float)(1e-32 / 6.0);
    const float pi_d = 3.14159265358979323846f / 1.1f;

    auto rowp = [&](int i) -> const float* {
        if (INT) return eps + (size_t)i * (size_t)Wn;
        int ic = i < 0 ? 0 : (i > Hn - 1 ? Hn - 1 : i);
        return eps + (size_t)ic * (size_t)Wn;
    };

    // rotation registers: col j rows i-2..i+2; cols j-1/j+1 rows i-1..i+1
    float c_mm, c_m, c_c, c_p, c_pp;
    float w_m, w_c, w_p, e_m, e_cc, e_p;
    {
        const float* rm2 = rowp(i0 - 2);
        const float* rm1 = rowp(i0 - 1);
        const float* rc0 = rowp(i0);
        const float* rp1 = rowp(i0 + 1);
        c_mm = rm2[j]; c_m = rm1[j]; c_c = rc0[j]; c_p = rp1[j];
        w_m = rm1[jm]; w_c = rc0[jm]; w_p = rp1[jm];
        e_m = rm1[cjp]; e_cc = rc0[cjp]; e_p = rp1[cjp];
    }

    float acc = 0.0f;
    #pragma unroll
    for (int r = 0; r < ROWS_PER; ++r) {
        const int i = i0 + r;
        const float* rcur = rowp(i);
        const float* rpp  = rowp(i + 2);
        c_pp = rpp[j];                 // new loads this step: 5 total
        const float ww = rcur[jmm];
        const float ee = rcur[cjpp];

        float sxi, sxm, sxp;
        if (INT) { sxi = rd2; sxm = rd2; sxp = rd2; }
        else {
            sxi = (i == 0 || i == Hn - 1) ? rd : rd2;
            sxm = (i <= 1) ? rd : rd2;
            sxp = (i >= Hn - 2) ? rd : rd2;
        }

        const float ex = fmaf(c_p - c_m, sxi, SC);
        const float ey = fmaf(e_cc - w_c, syj, SC);
        float exn = fmaf(c_c - c_mm, sxm, SC);
        float exs = fmaf(c_pp - c_c, sxp, SC);
        if (!INT) {
            if (i == 0)      exn = ex;   // im == i at top boundary
            if (i == Hn - 1) exs = ex;   // ip == i at bottom boundary
        }
        const float exx = (exs - exn) * sxi;
        float eyw = fmaf(c_c - ww, sym, SC);
        const float eye = fmaf(ee - c_c, syp, SC);
        if (j == 0) eyw = ey;            // jm == j at left boundary
        const float eyy = (eye - eyw) * syj;
        const float exy = ((e_p - e_m) - (w_p - w_m)) * (sxi * syj);

        const float t1 = ex * ex;
        const float t2 = ey * ey;
        const float pxy = ex * ey;
        float num = t1 * eyy;
        num = fmaf(t2, exx, num);
        num = fmaf(-2.0f * pxy, exy, num);

        const float ev2 = t1 + t2;
        float ev = __builtin_amdgcn_sqrtf(ev2);
        ev = fmaxf(ev, FLOORV);
        const float rv = __builtin_amdgcn_rcpf(ev);
        const float k  = num * (rv * rv) * rv;
        const float at = fast_atan_ratio(ev, c_c, rv);
        const float cc = fabsf(k * at) - pi_d;
        acc += fmaxf(cc, 0.0f);          // fmax(NaN,0)=0 -> nansum semantics

        // rotate down one row
        c_mm = c_m; c_m = c_c; c_c = c_p; c_p = c_pp;
        w_m = w_c; w_c = w_p;
        e_m = e_cc; e_cc = e_p;
        w_p = rpp[jm];                   // row i+2 for next iteration
        e_p = rpp[cjp];
    }
    return acc;
}

__global__ __launch_bounds__(BLOCK_X) void curve_kernel(
    const float* __restrict__ eps, const float* __restrict__ gs,
    double* __restrict__ ws, float* __restrict__ out,
    int Hn, int Wn, int nblocks)
{
    const int tx = threadIdx.x;
    const int j  = blockIdx.x * BLOCK_X + tx;
    const int i0 = blockIdx.y * ROWS_PER;
    const float d  = gs[0];
    const float rd = 1.0f / d;
    const float rd2 = 0.5f * rd;

    float accf = 0.0f;
    if (j < Wn) {
        const int jm  = (j > 0) ? j - 1 : 0;
        const int jmm = (j > 1) ? j - 2 : 0;
        const int jp = j + 1, jpp = j + 2;
        const int cjp  = (jp  < Wn) ? jp  : (2 * Wn - 1 - jp);   // mirror seam
        const int cjpp = (jpp < Wn) ? jpp : (2 * Wn - 1 - jpp);
        const float syj = (j == 0)  ? rd : rd2;
        const float sym = (jm == 0) ? rd : rd2;
        const float syp = rd2;   // jp never a boundary of the 2W virtual grid

        const bool interior = (blockIdx.y != 0) && (i0 + ROWS_PER + 1 < Hn);
        if (interior)
            accf = compute_rows<true >(eps, Hn, Wn, i0, j, jm, jmm, cjp, cjpp, rd, syj, sym, syp);
        else
            accf = compute_rows<false>(eps, Hn, Wn, i0, j, jm, jmm, cjp, cjpp, rd, syj, sym, syp);
    }

    double acc = (double)accf;
    #pragma unroll
    for (int off = 32; off > 0; off >>= 1)
        acc += __shfl_down(acc, off, 64);
    __shared__ double lds[BLOCK_X / 64];
    const int lane = tx & 63, wv = tx >> 6;
    if (lane == 0) lds[wv] = acc;
    __syncthreads();
    if (tx == 0) {
        double s = lds[0] + lds[1] + lds[2] + lds[3];
        __hip_atomic_fetch_add(ws, s, __ATOMIC_RELAXED, __HIP_MEMORY_SCOPE_AGENT);
        unsigned int old = __hip_atomic_fetch_add((unsigned int*)(ws + 1), 1u,
                                                  __ATOMIC_ACQ_REL, __HIP_MEMORY_SCOPE_AGENT);
        if (old == (unsigned int)nblocks - 1) {
            // all block partials are in; x2 for mirror half, x d^2 (ALPHA=1)
            double tot = __hip_atomic_load(ws, __ATOMIC_ACQUIRE, __HIP_MEMORY_SCOPE_AGENT);
            const double dd = (double)d;
            out[0] = (float)(tot * 2.0 * dd * dd);
        }
    }
}

extern "C" void kernel_launch(void* const* d_in, const int* in_sizes, int n_in,
                              void* d_out, int out_size, void* d_ws, size_t ws_size,
                              hipStream_t stream) {
    const float* eps = (const float*)d_in[0];
    const float* gs  = (const float*)d_in[1];
    float* out = (float*)d_out;

    const int n = in_sizes[0];
    int Wn = (int)(sqrt((double)n) + 0.5);   // 4096 for 4096x4096
    int Hn = n / Wn;

    const int gx = (Wn + BLOCK_X - 1) / BLOCK_X;     // 16
    const int gy = (Hn + ROWS_PER - 1) / ROWS_PER;   // 256

    // ws[0] = f64 total, ws+8 = arrival counter — zeroed every (graph) launch
    hipMemsetAsync(d_ws, 0, 16, stream);
    curve_kernel<<<dim3(gx, gy), BLOCK_X, 0, stream>>>(
        eps, gs, (double*)d_ws, out, Hn, Wn, gx * gy);
}